// Round 8
// baseline (1078.223 us; speedup 1.0000x reference)
//
#include <hip/hip_runtime.h>
#include <stdint.h>

// ---------------------------------------------------------------------------
// GINEncoder: 2x GINEConv(eps=0, MLP 128->128->128, edge_lin 32->128) + head.
//   1. CSR by dst: hist + two-level scan + scatter; edges packed int2{src,eid}.
//   2. agg_mfma: node-centric MFMA; 16 edges/chunk = one 16x16x32 A-fragment;
//      x[src] gathers batched into regs. R8: NW=8192 (8 blocks/CU, was 38% occ).
//   3. mlp2_mfma: fused GEMM pair; R8: 512-thr blocks, wave-pairs split the
//      nt dimension (4 col-tiles each per stage) -> 2x resident waves, halved
//      per-wave weight-fragment traffic. bf16x3 (fp32-accurate) throughout.
// edge_index is int64 in the reference but harness passes int32.
// ---------------------------------------------------------------------------

#define ND 128
#define ED 32

typedef __attribute__((ext_vector_type(8))) short short8;
typedef __attribute__((ext_vector_type(4))) float f32x4;

__device__ inline unsigned short bf16_hi(float f) {
    union { float f; unsigned u; } v;
    v.f = f;
    return (unsigned short)(v.u >> 16);  // truncation; residual captured by lo
}
__device__ inline float bf16_f(unsigned short h) {
    union { unsigned u; float f; } v;
    v.u = ((unsigned)h) << 16;
    return v.f;
}

__global__ __launch_bounds__(256) void zero_kernel(int* __restrict__ p, int n) {
    int i = blockIdx.x * blockDim.x + threadIdx.x;
    if (i < n) p[i] = 0;
}

__global__ __launch_bounds__(256) void hist_kernel(const int* __restrict__ ei,
                                                   int* __restrict__ counts, int E) {
    int i = blockIdx.x * blockDim.x + threadIdx.x;
    if (i < E) atomicAdd(&counts[ei[E + i]], 1);
}

// ---- two-level parallel scan over counts[N] ----
__global__ __launch_bounds__(256) void bsum_kernel(const int* __restrict__ counts,
                                                   int* __restrict__ bsum, int N) {
    __shared__ int s[256];
    int t = threadIdx.x;
    int i = blockIdx.x * 256 + t;
    s[t] = (i < N) ? counts[i] : 0;
    __syncthreads();
#pragma unroll
    for (int off = 128; off > 0; off >>= 1) {
        if (t < off) s[t] += s[t + off];
        __syncthreads();
    }
    if (t == 0) bsum[blockIdx.x] = s[0];
}

__global__ __launch_bounds__(256) void scan_bsums(const int* __restrict__ bsum,
                                                  int* __restrict__ bofs,
                                                  int* __restrict__ row_start_N, int NB) {
    __shared__ int s[256];
    int t = threadIdx.x;
    int chunk = (NB + 255) >> 8;
    int lo = min(t * chunk, NB);
    int hi = min(lo + chunk, NB);
    int sum = 0;
    for (int i = lo; i < hi; ++i) sum += bsum[i];
    s[t] = sum;
    __syncthreads();
    for (int off = 1; off < 256; off <<= 1) {
        int v = (t >= off) ? s[t - off] : 0;
        __syncthreads();
        s[t] += v;
        __syncthreads();
    }
    int pre = (t == 0) ? 0 : s[t - 1];
    for (int i = lo; i < hi; ++i) {
        bofs[i] = pre;
        pre += bsum[i];
    }
    if (t == 255) *row_start_N = s[255];
}

__global__ __launch_bounds__(256) void expand_kernel(const int* __restrict__ counts,
                                                     const int* __restrict__ bofs,
                                                     int* __restrict__ row_start,
                                                     int* __restrict__ woff, int N) {
    __shared__ int s[256];
    int t = threadIdx.x;
    int i = blockIdx.x * 256 + t;
    int c = (i < N) ? counts[i] : 0;
    s[t] = c;
    __syncthreads();
    for (int off = 1; off < 256; off <<= 1) {
        int v = (t >= off) ? s[t - off] : 0;
        __syncthreads();
        s[t] += v;
        __syncthreads();
    }
    if (i < N) {
        int pre = bofs[blockIdx.x] + s[t] - c;  // exclusive
        row_start[i] = pre;
        woff[i] = pre;
    }
}

__global__ __launch_bounds__(256) void scatter_kernel(const int* __restrict__ ei,
                                                      int* __restrict__ woff,
                                                      int2* __restrict__ pack, int E) {
    int i = blockIdx.x * blockDim.x + threadIdx.x;
    if (i < E) {
        int d = ei[E + i];
        int p = atomicAdd(&woff[d], 1);
        pack[p] = make_int2(ei[i], i);  // {src, eid}
    }
}

// Split 6 weight matrices [128,128] into bf16 hi/lo, MFMA B-fragment order:
// chunk c = nt*4+ks; lane l holds B[k=ks*32+(l>>4)*8+j][n=nt*16+(l&15)], j=0..7.
__global__ __launch_bounds__(256) void wprep_kernel(
    const float* __restrict__ w0, const float* __restrict__ w1,
    const float* __restrict__ w2, const float* __restrict__ w3,
    const float* __restrict__ w4, const float* __restrict__ w5,
    unsigned short* __restrict__ hi, unsigned short* __restrict__ lo) {
    int t = blockIdx.x * blockDim.x + threadIdx.x;  // 0..2047
    const float* W;
    switch (blockIdx.y) {
        case 0: W = w0; break;
        case 1: W = w1; break;
        case 2: W = w2; break;
        case 3: W = w3; break;
        case 4: W = w4; break;
        default: W = w5; break;
    }
    unsigned short* dh = hi + (size_t)blockIdx.y * 16384;
    unsigned short* dl = lo + (size_t)blockIdx.y * 16384;
    int c = t >> 6, l = t & 63;
    int nt = c >> 2, ks = c & 3;
    int n = nt * 16 + (l & 15);
    int kb = ks * 32 + ((l >> 4) << 3);
#pragma unroll
    for (int j = 0; j < 8; ++j) {
        float f = W[(size_t)(kb + j) * ND + n];
        unsigned short h = bf16_hi(f);
        dh[((size_t)c * 64 + l) * 8 + j] = h;
        dl[((size_t)c * 64 + l) * 8 + j] = bf16_hi(f - bf16_f(h));
    }
}

// Prep we [32,128] (2 matrices) into bf16-hi B-fragments: chunk = nt (8);
// lane l holds we[k=(l>>4)*8+j][n=nt*16+(l&15)].
__global__ __launch_bounds__(256) void wprep_we(const float* __restrict__ w0,
                                                const float* __restrict__ w1,
                                                unsigned short* __restrict__ hi) {
    int t = threadIdx.x;
    int c = (blockIdx.x << 2) + (t >> 6);  // nt 0..7
    int l = t & 63;
    const float* W = blockIdx.y ? w1 : w0;
    unsigned short* dh = hi + (size_t)blockIdx.y * 4096;
    int n = c * 16 + (l & 15);
    int kb = (l >> 4) << 3;
#pragma unroll
    for (int j = 0; j < 8; ++j)
        dh[((size_t)c * 64 + l) * 8 + j] = bf16_hi(W[(size_t)(kb + j) * ND + n]);
}

// Node-centric MFMA aggregation.
// h[v] = x[v] + sum_{e: dst=v} relu(x[src_e] + ea_e @ we + be)
__global__ __launch_bounds__(256, 8) void agg_mfma(
    const float* __restrict__ xin, const float* __restrict__ edge_attr,
    const unsigned short* __restrict__ bfh, const float* __restrict__ be,
    const int* __restrict__ row_start, const int2* __restrict__ pack,
    float* __restrict__ hout, int N, int NW) {
    int lane = threadIdx.x & 63;
    int gw = (blockIdx.x * blockDim.x + threadIdx.x) >> 6;
    int m = lane & 15;
    int quad = lane >> 4;

    // we fragments (bf16-hi), held in registers for the whole kernel
    short8 bh[8];
#pragma unroll
    for (int nt = 0; nt < 8; ++nt)
        bh[nt] = *(const short8*)(bfh + ((size_t)nt * 64 + lane) * 8);
    float ber[8];
#pragma unroll
    for (int nt = 0; nt < 8; ++nt) ber[nt] = be[nt * 16 + m];

    for (int v = gw; v < N; v += NW) {
        int beg = row_start[v];
        int end = row_start[v + 1];
        float part[8];
#pragma unroll
        for (int nt = 0; nt < 8; ++nt) part[nt] = 0.f;

        for (int base = beg; base < end; base += 16) {
            int rem = end - base;  // >= 1
            int mm = m < rem ? m : rem - 1;
            int2 pk = pack[base + mm];
            // src indices for my quad's 4 C-rows (edges quad*4+r), from lanes 0..15
            int s[4];
#pragma unroll
            for (int r = 0; r < 4; ++r) s[r] = __shfl(pk.x, quad * 4 + r, 64);

            // ---- batched loads: ea row (2x16B) + 32 x-gathers, one wait ----
            const float4* ar = (const float4*)(edge_attr + (size_t)pk.y * ED + quad * 8);
            float4 a0 = ar[0], a1 = ar[1];
            float xv[4][8];
#pragma unroll
            for (int r = 0; r < 4; ++r) {
                const float* xr = xin + (size_t)s[r] * ND + m;
#pragma unroll
                for (int nt = 0; nt < 8; ++nt) xv[r][nt] = xr[nt * 16];
            }

            // A fragment split hi/lo (exact)
            float af[8] = {a0.x, a0.y, a0.z, a0.w, a1.x, a1.y, a1.z, a1.w};
            short8 ah, al;
#pragma unroll
            for (int j = 0; j < 8; ++j) {
                unsigned short h = bf16_hi(af[j]);
                ah[j] = (short)h;
                al[j] = (short)bf16_hi(af[j] - bf16_f(h));
            }

#pragma unroll
            for (int nt = 0; nt < 8; ++nt) {
                f32x4 a = {0.f, 0.f, 0.f, 0.f};
                a = __builtin_amdgcn_mfma_f32_16x16x32_bf16(ah, bh[nt], a, 0, 0, 0);
                a = __builtin_amdgcn_mfma_f32_16x16x32_bf16(al, bh[nt], a, 0, 0, 0);
#pragma unroll
                for (int r = 0; r < 4; ++r) {
                    float vm = (quad * 4 + r) < rem ? 1.f : 0.f;
                    float msg = xv[r][nt] + a[r] + ber[nt];
                    msg = msg > 0.f ? msg : 0.f;
                    part[nt] = fmaf(msg, vm, part[nt]);
                }
            }
        }
        // reduce over quads (cols live in lanes m, m+16, m+32, m+48)
#pragma unroll
        for (int nt = 0; nt < 8; ++nt) {
            float p = part[nt];
            p += __shfl_xor(p, 16, 64);
            p += __shfl_xor(p, 32, 64);
            part[nt] = p;
        }
        // quad q writes cols of tiles 2q, 2q+1
        float o0 = quad == 0 ? part[0] : quad == 1 ? part[2] : quad == 2 ? part[4] : part[6];
        float o1 = quad == 0 ? part[1] : quad == 1 ? part[3] : quad == 2 ? part[5] : part[7];
        int col0 = quad * 32 + m;
        int col1 = col0 + 16;
        hout[(size_t)v * ND + col0] = xin[(size_t)v * ND + col0] + o0;
        hout[(size_t)v * ND + col1] = xin[(size_t)v * ND + col1] + o1;
    }
}

// Fused pair of GEMMs: C = maybe_relu2( relu(A@W1+b1) @ W2 + b2 ).
// 512-thread blocks = 8 waves = 4 pairs; each PAIR owns one 16-row tile and
// splits the 8 col-tiles (nt) between its 2 waves per stage. __syncthreads
// between stage1 (write LDS) and stage2 (read full LDS rows).
#define LP 132  // padded LDS row stride (floats); keeps 16B alignment, 2-way banks
__global__ __launch_bounds__(512, 4) void mlp2_mfma(
    const float* __restrict__ A,
    const unsigned short* __restrict__ w1h, const unsigned short* __restrict__ w1l,
    const float* __restrict__ b1,
    const unsigned short* __restrict__ w2h, const unsigned short* __restrict__ w2l,
    const float* __restrict__ b2,
    float* __restrict__ C, int N, int relu2) {
    __shared__ float tile[4][16 * LP];
    int t = threadIdx.x;
    int lane = t & 63;
    int wave = t >> 6;       // 0..7
    int pair = wave >> 1;    // 0..3
    int half = wave & 1;     // nt-half: nt = half*4 .. half*4+3
    int m0 = (blockIdx.x * 4 + pair) * 16;
    int m = lane & 15;
    int quad = lane >> 4;
    float* T = tile[pair];

    // ---- stage 1: load A rows (both waves of pair load same 16 rows; L1-hot) ----
    int row = m0 + m;
    bool rok = row < N;
    short8 ah[4], al[4];
#pragma unroll
    for (int ks = 0; ks < 4; ++ks) {
        float f[8];
        if (rok) {
            const float4* p = (const float4*)(A + (size_t)row * ND + ks * 32 + quad * 8);
            float4 a0 = p[0], a1 = p[1];
            f[0] = a0.x; f[1] = a0.y; f[2] = a0.z; f[3] = a0.w;
            f[4] = a1.x; f[5] = a1.y; f[6] = a1.z; f[7] = a1.w;
        } else {
#pragma unroll
            for (int j = 0; j < 8; ++j) f[j] = 0.f;
        }
#pragma unroll
        for (int j = 0; j < 8; ++j) {
            unsigned short hh = bf16_hi(f[j]);
            ah[ks][j] = (short)hh;
            al[ks][j] = (short)bf16_hi(f[j] - bf16_f(hh));
        }
    }

    // GEMM1 on my nt-half -> bias+relu -> LDS (C/D: col=lane&15, row=quad*4+r)
#pragma unroll
    for (int ntl = 0; ntl < 4; ++ntl) {
        int nt = half * 4 + ntl;
        f32x4 acc = {0.f, 0.f, 0.f, 0.f};
#pragma unroll
        for (int ks = 0; ks < 4; ++ks) {
            size_t off = ((size_t)(nt * 4 + ks) * 64 + lane) * 8;
            short8 bh = *(const short8*)(w1h + off);
            short8 bl = *(const short8*)(w1l + off);
            acc = __builtin_amdgcn_mfma_f32_16x16x32_bf16(ah[ks], bh, acc, 0, 0, 0);
            acc = __builtin_amdgcn_mfma_f32_16x16x32_bf16(al[ks], bh, acc, 0, 0, 0);
            acc = __builtin_amdgcn_mfma_f32_16x16x32_bf16(ah[ks], bl, acc, 0, 0, 0);
        }
        float bv = b1[nt * 16 + m];
#pragma unroll
        for (int r = 0; r < 4; ++r) {
            float o = acc[r] + bv;
            o = o > 0.f ? o : 0.f;
            T[(quad * 4 + r) * LP + nt * 16 + m] = o;
        }
    }

    __syncthreads();  // pair-partner's nt-half must land in T

    // ---- stage 2: full rows from LDS as A-fragments ----
    short8 ch[4], cl[4];
#pragma unroll
    for (int ks = 0; ks < 4; ++ks) {
        const float4* p = (const float4*)(T + m * LP + ks * 32 + quad * 8);
        float4 a0 = p[0], a1 = p[1];
        float f[8] = {a0.x, a0.y, a0.z, a0.w, a1.x, a1.y, a1.z, a1.w};
#pragma unroll
        for (int j = 0; j < 8; ++j) {
            unsigned short hh = bf16_hi(f[j]);
            ch[ks][j] = (short)hh;
            cl[ks][j] = (short)bf16_hi(f[j] - bf16_f(hh));
        }
    }

#pragma unroll
    for (int ntl = 0; ntl < 4; ++ntl) {
        int nt = half * 4 + ntl;
        f32x4 acc = {0.f, 0.f, 0.f, 0.f};
#pragma unroll
        for (int ks = 0; ks < 4; ++ks) {
            size_t off = ((size_t)(nt * 4 + ks) * 64 + lane) * 8;
            short8 bh = *(const short8*)(w2h + off);
            short8 bl = *(const short8*)(w2l + off);
            acc = __builtin_amdgcn_mfma_f32_16x16x32_bf16(ch[ks], bh, acc, 0, 0, 0);
            acc = __builtin_amdgcn_mfma_f32_16x16x32_bf16(cl[ks], bh, acc, 0, 0, 0);
            acc = __builtin_amdgcn_mfma_f32_16x16x32_bf16(ch[ks], bl, acc, 0, 0, 0);
        }
        float bv = b2[nt * 16 + m];
#pragma unroll
        for (int r = 0; r < 4; ++r) {
            int rr = m0 + quad * 4 + r;
            if (rr < N) {
                float o = acc[r] + bv;
                if (relu2) o = o > 0.f ? o : 0.f;
                C[(size_t)rr * ND + nt * 16 + m] = o;
            }
        }
    }
}

extern "C" void kernel_launch(void* const* d_in, const int* in_sizes, int n_in,
                              void* d_out, int out_size, void* d_ws, size_t ws_size,
                              hipStream_t stream) {
    const float* x = (const float*)d_in[0];
    const int* ei = (const int*)d_in[1];  // int64 in reference -> int32 from harness
    const float* ea = (const float*)d_in[2];
    const float* w1_0 = (const float*)d_in[3];
    const float* b1_0 = (const float*)d_in[4];
    const float* w2_0 = (const float*)d_in[5];
    const float* b2_0 = (const float*)d_in[6];
    const float* we_0 = (const float*)d_in[7];
    const float* be_0 = (const float*)d_in[8];
    const float* w1_1 = (const float*)d_in[9];
    const float* b1_1 = (const float*)d_in[10];
    const float* w2_1 = (const float*)d_in[11];
    const float* b2_1 = (const float*)d_in[12];
    const float* we_1 = (const float*)d_in[13];
    const float* be_1 = (const float*)d_in[14];
    const float* fc1_w = (const float*)d_in[15];
    const float* fc1_b = (const float*)d_in[16];
    const float* fc2_w = (const float*)d_in[17];
    const float* fc2_b = (const float*)d_in[18];

    int N = in_sizes[0] / ND;
    int E = in_sizes[2] / ED;
    int NB = (N + 255) / 256;

    float* bufA = (float*)d_ws;
    int* counts = (int*)(bufA + (size_t)N * ND);
    int* row_start = counts + N;
    int* woff = row_start + (N + 1);
    int* bsum = woff + N;
    int* bofs = bsum + NB;
    int2* pack = (int2*)((((uintptr_t)(bofs + NB)) + 15) & ~(uintptr_t)15);
    unsigned short* wfh = (unsigned short*)(pack + E);
    unsigned short* wfl = wfh + 6 * 16384;
    unsigned short* weh = wfl + 6 * 16384;  // 2 * 4096
    float* out = (float*)d_out;

    // ---- CSR build (two-level parallel scan) + weight prep ----
    zero_kernel<<<(N + 255) / 256, 256, 0, stream>>>(counts, N);
    hist_kernel<<<(E + 255) / 256, 256, 0, stream>>>(ei, counts, E);
    bsum_kernel<<<NB, 256, 0, stream>>>(counts, bsum, N);
    scan_bsums<<<1, 256, 0, stream>>>(bsum, bofs, row_start + N, NB);
    expand_kernel<<<NB, 256, 0, stream>>>(counts, bofs, row_start, woff, N);
    scatter_kernel<<<(E + 255) / 256, 256, 0, stream>>>(ei, woff, pack, E);
    wprep_kernel<<<dim3(8, 6), 256, 0, stream>>>(w1_0, w2_0, w1_1, w2_1, fc1_w, fc2_w,
                                                 wfh, wfl);
    wprep_we<<<dim3(2, 2), 256, 0, stream>>>(we_0, we_1, weh);

    const int NW = 8192;  // agg waves (2048 blocks = 8 blocks/CU, VGPR=64 fits)
    int gg = (N + 63) / 64;  // mlp2 blocks: 4 row-tiles (pairs) x 16 rows

    // ---- layer 0 ----  agg0: x -> out; mlp0: out -> bufA
    agg_mfma<<<NW / 4, 256, 0, stream>>>(x, ea, weh, be_0, row_start, pack, out, N, NW);
    mlp2_mfma<<<gg, 512, 0, stream>>>(out, wfh + 0 * 16384, wfl + 0 * 16384, b1_0,
                                      wfh + 1 * 16384, wfl + 1 * 16384, b2_0, bufA, N, 1);

    // ---- layer 1 ----  agg1: bufA -> out; mlp1: out -> bufA
    agg_mfma<<<NW / 4, 256, 0, stream>>>(bufA, ea, weh + 4096, be_1, row_start, pack, out,
                                         N, NW);
    mlp2_mfma<<<gg, 512, 0, stream>>>(out, wfh + 2 * 16384, wfl + 2 * 16384, b1_1,
                                      wfh + 3 * 16384, wfl + 3 * 16384, b2_1, bufA, N, 1);

    // ---- head ----  bufA -> out (final)
    mlp2_mfma<<<gg, 512, 0, stream>>>(bufA, wfh + 4 * 16384, wfl + 4 * 16384, fc1_b,
                                      wfh + 5 * 16384, wfl + 5 * 16384, fc2_b, out, N, 0);
}

// Round 9
// 483.785 us; speedup vs baseline: 2.2287x; 2.2287x over previous
//
#include <hip/hip_runtime.h>
#include <stdint.h>

// ---------------------------------------------------------------------------
// GINEncoder: 2x GINEConv(eps=0, MLP 128->128->128, edge_lin 32->128) + head.
//   1. CSR by dst: hist + two-level scan + scatter; edges packed int2{src,eid}.
//   2. agg_mfma: node-centric MFMA; 16 edges/chunk = one 16x16x32 A-fragment;
//      x[src] gathers batched into regs. NW=8192 (2048 blocks).
//      R9: launch_bounds back to (256,4) — (256,8) forced VGPR 64->32 and
//      spilled to scratch (FETCH 188->923MB, WRITE 25->536MB, 4x slower).
//      At 64 VGPR the HW already fits 8 blocks/CU; R7 was merely grid-limited.
//   3. mlp2_mfma: fused GEMM pair; 512-thr blocks, wave-pairs split nt.
// edge_index is int64 in the reference but harness passes int32.
// ---------------------------------------------------------------------------

#define ND 128
#define ED 32

typedef __attribute__((ext_vector_type(8))) short short8;
typedef __attribute__((ext_vector_type(4))) float f32x4;

__device__ inline unsigned short bf16_hi(float f) {
    union { float f; unsigned u; } v;
    v.f = f;
    return (unsigned short)(v.u >> 16);  // truncation; residual captured by lo
}
__device__ inline float bf16_f(unsigned short h) {
    union { unsigned u; float f; } v;
    v.u = ((unsigned)h) << 16;
    return v.f;
}

__global__ __launch_bounds__(256) void zero_kernel(int* __restrict__ p, int n) {
    int i = blockIdx.x * blockDim.x + threadIdx.x;
    if (i < n) p[i] = 0;
}

__global__ __launch_bounds__(256) void hist_kernel(const int* __restrict__ ei,
                                                   int* __restrict__ counts, int E) {
    int i = blockIdx.x * blockDim.x + threadIdx.x;
    if (i < E) atomicAdd(&counts[ei[E + i]], 1);
}

// ---- two-level parallel scan over counts[N] ----
__global__ __launch_bounds__(256) void bsum_kernel(const int* __restrict__ counts,
                                                   int* __restrict__ bsum, int N) {
    __shared__ int s[256];
    int t = threadIdx.x;
    int i = blockIdx.x * 256 + t;
    s[t] = (i < N) ? counts[i] : 0;
    __syncthreads();
#pragma unroll
    for (int off = 128; off > 0; off >>= 1) {
        if (t < off) s[t] += s[t + off];
        __syncthreads();
    }
    if (t == 0) bsum[blockIdx.x] = s[0];
}

__global__ __launch_bounds__(256) void scan_bsums(const int* __restrict__ bsum,
                                                  int* __restrict__ bofs,
                                                  int* __restrict__ row_start_N, int NB) {
    __shared__ int s[256];
    int t = threadIdx.x;
    int chunk = (NB + 255) >> 8;
    int lo = min(t * chunk, NB);
    int hi = min(lo + chunk, NB);
    int sum = 0;
    for (int i = lo; i < hi; ++i) sum += bsum[i];
    s[t] = sum;
    __syncthreads();
    for (int off = 1; off < 256; off <<= 1) {
        int v = (t >= off) ? s[t - off] : 0;
        __syncthreads();
        s[t] += v;
        __syncthreads();
    }
    int pre = (t == 0) ? 0 : s[t - 1];
    for (int i = lo; i < hi; ++i) {
        bofs[i] = pre;
        pre += bsum[i];
    }
    if (t == 255) *row_start_N = s[255];
}

__global__ __launch_bounds__(256) void expand_kernel(const int* __restrict__ counts,
                                                     const int* __restrict__ bofs,
                                                     int* __restrict__ row_start,
                                                     int* __restrict__ woff, int N) {
    __shared__ int s[256];
    int t = threadIdx.x;
    int i = blockIdx.x * 256 + t;
    int c = (i < N) ? counts[i] : 0;
    s[t] = c;
    __syncthreads();
    for (int off = 1; off < 256; off <<= 1) {
        int v = (t >= off) ? s[t - off] : 0;
        __syncthreads();
        s[t] += v;
        __syncthreads();
    }
    if (i < N) {
        int pre = bofs[blockIdx.x] + s[t] - c;  // exclusive
        row_start[i] = pre;
        woff[i] = pre;
    }
}

__global__ __launch_bounds__(256) void scatter_kernel(const int* __restrict__ ei,
                                                      int* __restrict__ woff,
                                                      int2* __restrict__ pack, int E) {
    int i = blockIdx.x * blockDim.x + threadIdx.x;
    if (i < E) {
        int d = ei[E + i];
        int p = atomicAdd(&woff[d], 1);
        pack[p] = make_int2(ei[i], i);  // {src, eid}
    }
}

// Split 6 weight matrices [128,128] into bf16 hi/lo, MFMA B-fragment order:
// chunk c = nt*4+ks; lane l holds B[k=ks*32+(l>>4)*8+j][n=nt*16+(l&15)], j=0..7.
__global__ __launch_bounds__(256) void wprep_kernel(
    const float* __restrict__ w0, const float* __restrict__ w1,
    const float* __restrict__ w2, const float* __restrict__ w3,
    const float* __restrict__ w4, const float* __restrict__ w5,
    unsigned short* __restrict__ hi, unsigned short* __restrict__ lo) {
    int t = blockIdx.x * blockDim.x + threadIdx.x;  // 0..2047
    const float* W;
    switch (blockIdx.y) {
        case 0: W = w0; break;
        case 1: W = w1; break;
        case 2: W = w2; break;
        case 3: W = w3; break;
        case 4: W = w4; break;
        default: W = w5; break;
    }
    unsigned short* dh = hi + (size_t)blockIdx.y * 16384;
    unsigned short* dl = lo + (size_t)blockIdx.y * 16384;
    int c = t >> 6, l = t & 63;
    int nt = c >> 2, ks = c & 3;
    int n = nt * 16 + (l & 15);
    int kb = ks * 32 + ((l >> 4) << 3);
#pragma unroll
    for (int j = 0; j < 8; ++j) {
        float f = W[(size_t)(kb + j) * ND + n];
        unsigned short h = bf16_hi(f);
        dh[((size_t)c * 64 + l) * 8 + j] = h;
        dl[((size_t)c * 64 + l) * 8 + j] = bf16_hi(f - bf16_f(h));
    }
}

// Prep we [32,128] (2 matrices) into bf16-hi B-fragments: chunk = nt (8);
// lane l holds we[k=(l>>4)*8+j][n=nt*16+(l&15)].
__global__ __launch_bounds__(256) void wprep_we(const float* __restrict__ w0,
                                                const float* __restrict__ w1,
                                                unsigned short* __restrict__ hi) {
    int t = threadIdx.x;
    int c = (blockIdx.x << 2) + (t >> 6);  // nt 0..7
    int l = t & 63;
    const float* W = blockIdx.y ? w1 : w0;
    unsigned short* dh = hi + (size_t)blockIdx.y * 4096;
    int n = c * 16 + (l & 15);
    int kb = (l >> 4) << 3;
#pragma unroll
    for (int j = 0; j < 8; ++j)
        dh[((size_t)c * 64 + l) * 8 + j] = bf16_hi(W[(size_t)(kb + j) * ND + n]);
}

// Node-centric MFMA aggregation.
// h[v] = x[v] + sum_{e: dst=v} relu(x[src_e] + ea_e @ we + be)
__global__ __launch_bounds__(256, 4) void agg_mfma(
    const float* __restrict__ xin, const float* __restrict__ edge_attr,
    const unsigned short* __restrict__ bfh, const float* __restrict__ be,
    const int* __restrict__ row_start, const int2* __restrict__ pack,
    float* __restrict__ hout, int N, int NW) {
    int lane = threadIdx.x & 63;
    int gw = (blockIdx.x * blockDim.x + threadIdx.x) >> 6;
    int m = lane & 15;
    int quad = lane >> 4;

    // we fragments (bf16-hi), held in registers for the whole kernel
    short8 bh[8];
#pragma unroll
    for (int nt = 0; nt < 8; ++nt)
        bh[nt] = *(const short8*)(bfh + ((size_t)nt * 64 + lane) * 8);
    float ber[8];
#pragma unroll
    for (int nt = 0; nt < 8; ++nt) ber[nt] = be[nt * 16 + m];

    for (int v = gw; v < N; v += NW) {
        int beg = row_start[v];
        int end = row_start[v + 1];
        float part[8];
#pragma unroll
        for (int nt = 0; nt < 8; ++nt) part[nt] = 0.f;

        for (int base = beg; base < end; base += 16) {
            int rem = end - base;  // >= 1
            int mm = m < rem ? m : rem - 1;
            int2 pk = pack[base + mm];
            // src indices for my quad's 4 C-rows (edges quad*4+r), from lanes 0..15
            int s[4];
#pragma unroll
            for (int r = 0; r < 4; ++r) s[r] = __shfl(pk.x, quad * 4 + r, 64);

            // ---- batched loads: ea row (2x16B) + 32 x-gathers, one wait ----
            const float4* ar = (const float4*)(edge_attr + (size_t)pk.y * ED + quad * 8);
            float4 a0 = ar[0], a1 = ar[1];
            float xv[4][8];
#pragma unroll
            for (int r = 0; r < 4; ++r) {
                const float* xr = xin + (size_t)s[r] * ND + m;
#pragma unroll
                for (int nt = 0; nt < 8; ++nt) xv[r][nt] = xr[nt * 16];
            }

            // A fragment split hi/lo (exact)
            float af[8] = {a0.x, a0.y, a0.z, a0.w, a1.x, a1.y, a1.z, a1.w};
            short8 ah, al;
#pragma unroll
            for (int j = 0; j < 8; ++j) {
                unsigned short h = bf16_hi(af[j]);
                ah[j] = (short)h;
                al[j] = (short)bf16_hi(af[j] - bf16_f(h));
            }

#pragma unroll
            for (int nt = 0; nt < 8; ++nt) {
                f32x4 a = {0.f, 0.f, 0.f, 0.f};
                a = __builtin_amdgcn_mfma_f32_16x16x32_bf16(ah, bh[nt], a, 0, 0, 0);
                a = __builtin_amdgcn_mfma_f32_16x16x32_bf16(al, bh[nt], a, 0, 0, 0);
#pragma unroll
                for (int r = 0; r < 4; ++r) {
                    float vm = (quad * 4 + r) < rem ? 1.f : 0.f;
                    float msg = xv[r][nt] + a[r] + ber[nt];
                    msg = msg > 0.f ? msg : 0.f;
                    part[nt] = fmaf(msg, vm, part[nt]);
                }
            }
        }
        // reduce over quads (cols live in lanes m, m+16, m+32, m+48)
#pragma unroll
        for (int nt = 0; nt < 8; ++nt) {
            float p = part[nt];
            p += __shfl_xor(p, 16, 64);
            p += __shfl_xor(p, 32, 64);
            part[nt] = p;
        }
        // quad q writes cols of tiles 2q, 2q+1
        float o0 = quad == 0 ? part[0] : quad == 1 ? part[2] : quad == 2 ? part[4] : part[6];
        float o1 = quad == 0 ? part[1] : quad == 1 ? part[3] : quad == 2 ? part[5] : part[7];
        int col0 = quad * 32 + m;
        int col1 = col0 + 16;
        hout[(size_t)v * ND + col0] = xin[(size_t)v * ND + col0] + o0;
        hout[(size_t)v * ND + col1] = xin[(size_t)v * ND + col1] + o1;
    }
}

// Fused pair of GEMMs: C = maybe_relu2( relu(A@W1+b1) @ W2 + b2 ).
// 512-thread blocks = 8 waves = 4 pairs; each PAIR owns one 16-row tile and
// splits the 8 col-tiles (nt) between its 2 waves per stage. __syncthreads
// between stage1 (write LDS) and stage2 (read full LDS rows).
#define LP 132  // padded LDS row stride (floats); keeps 16B alignment, 2-way banks
__global__ __launch_bounds__(512, 4) void mlp2_mfma(
    const float* __restrict__ A,
    const unsigned short* __restrict__ w1h, const unsigned short* __restrict__ w1l,
    const float* __restrict__ b1,
    const unsigned short* __restrict__ w2h, const unsigned short* __restrict__ w2l,
    const float* __restrict__ b2,
    float* __restrict__ C, int N, int relu2) {
    __shared__ float tile[4][16 * LP];
    int t = threadIdx.x;
    int lane = t & 63;
    int wave = t >> 6;       // 0..7
    int pair = wave >> 1;    // 0..3
    int half = wave & 1;     // nt-half: nt = half*4 .. half*4+3
    int m0 = (blockIdx.x * 4 + pair) * 16;
    int m = lane & 15;
    int quad = lane >> 4;
    float* T = tile[pair];

    // ---- stage 1: load A rows (both waves of pair load same 16 rows; L1-hot) ----
    int row = m0 + m;
    bool rok = row < N;
    short8 ah[4], al[4];
#pragma unroll
    for (int ks = 0; ks < 4; ++ks) {
        float f[8];
        if (rok) {
            const float4* p = (const float4*)(A + (size_t)row * ND + ks * 32 + quad * 8);
            float4 a0 = p[0], a1 = p[1];
            f[0] = a0.x; f[1] = a0.y; f[2] = a0.z; f[3] = a0.w;
            f[4] = a1.x; f[5] = a1.y; f[6] = a1.z; f[7] = a1.w;
        } else {
#pragma unroll
            for (int j = 0; j < 8; ++j) f[j] = 0.f;
        }
#pragma unroll
        for (int j = 0; j < 8; ++j) {
            unsigned short hh = bf16_hi(f[j]);
            ah[ks][j] = (short)hh;
            al[ks][j] = (short)bf16_hi(f[j] - bf16_f(hh));
        }
    }

    // GEMM1 on my nt-half -> bias+relu -> LDS (C/D: col=lane&15, row=quad*4+r)
#pragma unroll
    for (int ntl = 0; ntl < 4; ++ntl) {
        int nt = half * 4 + ntl;
        f32x4 acc = {0.f, 0.f, 0.f, 0.f};
#pragma unroll
        for (int ks = 0; ks < 4; ++ks) {
            size_t off = ((size_t)(nt * 4 + ks) * 64 + lane) * 8;
            short8 bh = *(const short8*)(w1h + off);
            short8 bl = *(const short8*)(w1l + off);
            acc = __builtin_amdgcn_mfma_f32_16x16x32_bf16(ah[ks], bh, acc, 0, 0, 0);
            acc = __builtin_amdgcn_mfma_f32_16x16x32_bf16(al[ks], bh, acc, 0, 0, 0);
            acc = __builtin_amdgcn_mfma_f32_16x16x32_bf16(ah[ks], bl, acc, 0, 0, 0);
        }
        float bv = b1[nt * 16 + m];
#pragma unroll
        for (int r = 0; r < 4; ++r) {
            float o = acc[r] + bv;
            o = o > 0.f ? o : 0.f;
            T[(quad * 4 + r) * LP + nt * 16 + m] = o;
        }
    }

    __syncthreads();  // pair-partner's nt-half must land in T

    // ---- stage 2: full rows from LDS as A-fragments ----
    short8 ch[4], cl[4];
#pragma unroll
    for (int ks = 0; ks < 4; ++ks) {
        const float4* p = (const float4*)(T + m * LP + ks * 32 + quad * 8);
        float4 a0 = p[0], a1 = p[1];
        float f[8] = {a0.x, a0.y, a0.z, a0.w, a1.x, a1.y, a1.z, a1.w};
#pragma unroll
        for (int j = 0; j < 8; ++j) {
            unsigned short hh = bf16_hi(f[j]);
            ch[ks][j] = (short)hh;
            cl[ks][j] = (short)bf16_hi(f[j] - bf16_f(hh));
        }
    }

#pragma unroll
    for (int ntl = 0; ntl < 4; ++ntl) {
        int nt = half * 4 + ntl;
        f32x4 acc = {0.f, 0.f, 0.f, 0.f};
#pragma unroll
        for (int ks = 0; ks < 4; ++ks) {
            size_t off = ((size_t)(nt * 4 + ks) * 64 + lane) * 8;
            short8 bh = *(const short8*)(w2h + off);
            short8 bl = *(const short8*)(w2l + off);
            acc = __builtin_amdgcn_mfma_f32_16x16x32_bf16(ch[ks], bh, acc, 0, 0, 0);
            acc = __builtin_amdgcn_mfma_f32_16x16x32_bf16(cl[ks], bh, acc, 0, 0, 0);
            acc = __builtin_amdgcn_mfma_f32_16x16x32_bf16(ch[ks], bl, acc, 0, 0, 0);
        }
        float bv = b2[nt * 16 + m];
#pragma unroll
        for (int r = 0; r < 4; ++r) {
            int rr = m0 + quad * 4 + r;
            if (rr < N) {
                float o = acc[r] + bv;
                if (relu2) o = o > 0.f ? o : 0.f;
                C[(size_t)rr * ND + nt * 16 + m] = o;
            }
        }
    }
}

extern "C" void kernel_launch(void* const* d_in, const int* in_sizes, int n_in,
                              void* d_out, int out_size, void* d_ws, size_t ws_size,
                              hipStream_t stream) {
    const float* x = (const float*)d_in[0];
    const int* ei = (const int*)d_in[1];  // int64 in reference -> int32 from harness
    const float* ea = (const float*)d_in[2];
    const float* w1_0 = (const float*)d_in[3];
    const float* b1_0 = (const float*)d_in[4];
    const float* w2_0 = (const float*)d_in[5];
    const float* b2_0 = (const float*)d_in[6];
    const float* we_0 = (const float*)d_in[7];
    const float* be_0 = (const float*)d_in[8];
    const float* w1_1 = (const float*)d_in[9];
    const float* b1_1 = (const float*)d_in[10];
    const float* w2_1 = (const float*)d_in[11];
    const float* b2_1 = (const float*)d_in[12];
    const float* we_1 = (const float*)d_in[13];
    const float* be_1 = (const float*)d_in[14];
    const float* fc1_w = (const float*)d_in[15];
    const float* fc1_b = (const float*)d_in[16];
    const float* fc2_w = (const float*)d_in[17];
    const float* fc2_b = (const float*)d_in[18];

    int N = in_sizes[0] / ND;
    int E = in_sizes[2] / ED;
    int NB = (N + 255) / 256;

    float* bufA = (float*)d_ws;
    int* counts = (int*)(bufA + (size_t)N * ND);
    int* row_start = counts + N;
    int* woff = row_start + (N + 1);
    int* bsum = woff + N;
    int* bofs = bsum + NB;
    int2* pack = (int2*)((((uintptr_t)(bofs + NB)) + 15) & ~(uintptr_t)15);
    unsigned short* wfh = (unsigned short*)(pack + E);
    unsigned short* wfl = wfh + 6 * 16384;
    unsigned short* weh = wfl + 6 * 16384;  // 2 * 4096
    float* out = (float*)d_out;

    // ---- CSR build (two-level parallel scan) + weight prep ----
    zero_kernel<<<(N + 255) / 256, 256, 0, stream>>>(counts, N);
    hist_kernel<<<(E + 255) / 256, 256, 0, stream>>>(ei, counts, E);
    bsum_kernel<<<NB, 256, 0, stream>>>(counts, bsum, N);
    scan_bsums<<<1, 256, 0, stream>>>(bsum, bofs, row_start + N, NB);
    expand_kernel<<<NB, 256, 0, stream>>>(counts, bofs, row_start, woff, N);
    scatter_kernel<<<(E + 255) / 256, 256, 0, stream>>>(ei, woff, pack, E);
    wprep_kernel<<<dim3(8, 6), 256, 0, stream>>>(w1_0, w2_0, w1_1, w2_1, fc1_w, fc2_w,
                                                 wfh, wfl);
    wprep_we<<<dim3(2, 2), 256, 0, stream>>>(we_0, we_1, weh);

    const int NW = 8192;  // 2048 blocks; at 64 VGPR the HW fits 8 blocks/CU
    int gg = (N + 63) / 64;  // mlp2 blocks: 4 row-tiles (pairs) x 16 rows

    // ---- layer 0 ----  agg0: x -> out; mlp0: out -> bufA
    agg_mfma<<<NW / 4, 256, 0, stream>>>(x, ea, weh, be_0, row_start, pack, out, N, NW);
    mlp2_mfma<<<gg, 512, 0, stream>>>(out, wfh + 0 * 16384, wfl + 0 * 16384, b1_0,
                                      wfh + 1 * 16384, wfl + 1 * 16384, b2_0, bufA, N, 1);

    // ---- layer 1 ----  agg1: bufA -> out; mlp1: out -> bufA
    agg_mfma<<<NW / 4, 256, 0, stream>>>(bufA, ea, weh + 4096, be_1, row_start, pack, out,
                                         N, NW);
    mlp2_mfma<<<gg, 512, 0, stream>>>(out, wfh + 2 * 16384, wfl + 2 * 16384, b1_1,
                                      wfh + 3 * 16384, wfl + 3 * 16384, b2_1, bufA, N, 1);

    // ---- head ----  bufA -> out (final)
    mlp2_mfma<<<gg, 512, 0, stream>>>(bufA, wfh + 4 * 16384, wfl + 4 * 16384, fc1_b,
                                      wfh + 5 * 16384, wfl + 5 * 16384, fc2_b, out, N, 0);
}